// Round 22
// baseline (155.452 us; speedup 1.0000x reference)
//
#include <hip/hip_runtime.h>
#include <hip/hip_bf16.h>

#define DMODEL 1024
#define NHEAD 16
#define HDIM 64
#define CTXLEN 2048
#define BATCH 2
#define M_TOTAL (BATCH * CTXLEN)   // 4096

typedef unsigned short ushort_t;
typedef __attribute__((ext_vector_type(8))) _Float16 f16x8;
typedef __attribute__((ext_vector_type(8))) unsigned short u16x8;
typedef __attribute__((ext_vector_type(4))) float f32x4;
typedef __attribute__((ext_vector_type(4))) unsigned short u16x4;

#define SCALE_LOG2 11.5415603271f   // 8 * log2(e) — folded into q at GEMM epilogue

__device__ __forceinline__ unsigned short f32_f16(float f) {
    return __builtin_bit_cast(unsigned short, (_Float16)f);
}
__device__ __forceinline__ float f16_f32(unsigned short h) {
    return (float)__builtin_bit_cast(_Float16, h);
}
__device__ __forceinline__ float fast_exp2(float x) {
    return __builtin_amdgcn_exp2f(x);
}
__device__ __forceinline__ f32x4 mfma16f(f16x8 a, f16x8 b, f32x4 c) {
    return __builtin_amdgcn_mfma_f32_16x16x32_f16(a, b, c, 0, 0, 0);
}
__device__ __forceinline__ void gload_lds16(const ushort_t* g, ushort_t* l) {
    __builtin_amdgcn_global_load_lds(
        (const __attribute__((address_space(1))) void*)g,
        (__attribute__((address_space(3))) void*)l, 16, 0, 0);
}
// units per q-tile: nu = qt/8+1; slot offset of first unit of qt within a bh
__device__ __forceinline__ int unit_off(int qt) {
    if (qt < 8)  return qt;
    if (qt < 16) return 8 + (qt - 8) * 2;
    if (qt < 24) return 24 + (qt - 16) * 3;
    return 48 + (qt - 24) * 4;
}

// ---------------------------------------------------------------------------
// fused f32 -> f16 convert for 3 arrays (one launch)
// ---------------------------------------------------------------------------
__global__ __launch_bounds__(256)
void conv3_f32_f16(const float* __restrict__ a, ushort_t* __restrict__ da, int na4,
                   const float* __restrict__ b, ushort_t* __restrict__ db, int nb4,
                   const float* __restrict__ c, ushort_t* __restrict__ dc, int nc4) {
    const int n = na4 + nb4 + nc4;
    for (int i = blockIdx.x * blockDim.x + threadIdx.x; i < n;
         i += gridDim.x * blockDim.x) {
        const float* s; ushort_t* d; int j = i;
        if (j < na4) { s = a; d = da; }
        else if (j - na4 < nb4) { j -= na4; s = b; d = db; }
        else { j -= na4 + nb4; s = c; d = dc; }
        const float4 v = reinterpret_cast<const float4*>(s)[j];
        u16x4 o;
        o[0] = f32_f16(v.x); o[1] = f32_f16(v.y);
        o[2] = f32_f16(v.z); o[3] = f32_f16(v.w);
        reinterpret_cast<u16x4*>(d)[j] = o;
    }
}

// ---------------------------------------------------------------------------
// fp16 MFMA GEMM (NT): C = A·B^T. BM=128, BN template (128 or 64), BK=64.
// XCD-aware bijective block swizzle. QKV_EPI: sec block-uniform;
//   sec 0/1: scatter q (prescaled) / k.  sec 2: V-transpose fused via LDS.
// (R21 baseline verbatim.)
// ---------------------------------------------------------------------------
template<int BN, bool QKV_EPI>
__global__ __launch_bounds__(256)
void gemm_f16_nt(const ushort_t* __restrict__ A, const ushort_t* __restrict__ B,
                 const float* __restrict__ bias, float* __restrict__ C,
                 ushort_t* __restrict__ qf, ushort_t* __restrict__ kf,
                 ushort_t* __restrict__ vt,
                 int M, int N, int K) {
    constexpr int NF = BN / 32;
    constexpr int BOFF = 8192;
    constexpr int BCHUNK = BN * 8;
    constexpr int LDSZ = QKV_EPI ? 17408 : (BOFF + BN * 64);
    __shared__ ushort_t lds[LDSZ];

    int bx, by;
    {
        const int gx  = gridDim.x;
        const int nwg = gx * (int)gridDim.y;
        const int cpx = nwg >> 3;
        int flat = (int)blockIdx.y * gx + (int)blockIdx.x;
        flat = (flat & 7) * cpx + (flat >> 3);
        bx = flat % gx;
        by = flat / gx;
    }

    const int tid  = threadIdx.x;
    const int lane = tid & 63;
    const int wave = tid >> 6;
    const int lc   = lane & 15;
    const int lg   = lane >> 4;
    const int wr   = wave >> 1;
    const int wc   = wave & 1;
    const int row0 = by * 128;
    const int col0 = bx * BN;

    int aoff[4][2], boff[NF][2];
    #pragma unroll
    for (int m = 0; m < 4; ++m) {
        const int ra = wr * 64 + m * 16 + lc;
        #pragma unroll
        for (int kk = 0; kk < 2; ++kk)
            aoff[m][kk] = ra * 64 + (((kk * 4 + lg) ^ (ra & 7)) * 8);
    }
    #pragma unroll
    for (int n = 0; n < NF; ++n) {
        const int rb = wc * (NF * 16) + n * 16 + lc;
        #pragma unroll
        for (int kk = 0; kk < 2; ++kk)
            boff[n][kk] = rb * 64 + (((kk * 4 + lg) ^ (rb & 7)) * 8);
    }

    f32x4 acc[4][NF];
    const f32x4 zero4 = {0.f, 0.f, 0.f, 0.f};
    #pragma unroll
    for (int m = 0; m < 4; ++m)
        #pragma unroll
        for (int n = 0; n < NF; ++n) acc[m][n] = zero4;

    const int NT = K >> 6;

    auto stage = [&](int kt) {
        const int ko = kt * 64;
        #pragma unroll
        for (int i = 0; i < 4; ++i) {
            const int c  = tid + i * 256;
            const int r  = c >> 3;
            const int sg = (c & 7) ^ (r & 7);
            gload_lds16(A + (size_t)(row0 + r) * K + ko + sg * 8, &lds[c * 8]);
        }
        #pragma unroll
        for (int i = 0; i < BCHUNK / 256; ++i) {
            const int c  = tid + i * 256;
            const int r  = c >> 3;
            const int sg = (c & 7) ^ (r & 7);
            gload_lds16(B + (size_t)(col0 + r) * K + ko + sg * 8, &lds[BOFF + c * 8]);
        }
    };

    stage(0);
    for (int kt = 0; kt < NT; ++kt) {
        __syncthreads();
        f16x8 fa[2][4], fb[2][NF];
        #pragma unroll
        for (int kk = 0; kk < 2; ++kk) {
            #pragma unroll
            for (int m = 0; m < 4; ++m)
                fa[kk][m] = *reinterpret_cast<const f16x8*>(&lds[aoff[m][kk]]);
            #pragma unroll
            for (int n = 0; n < NF; ++n)
                fb[kk][n] = *reinterpret_cast<const f16x8*>(&lds[BOFF + boff[n][kk]]);
        }
        __syncthreads();
        if (kt + 1 < NT) stage(kt + 1);
        #pragma unroll
        for (int kk = 0; kk < 2; ++kk)
            #pragma unroll
            for (int m = 0; m < 4; ++m)
                #pragma unroll
                for (int n = 0; n < NF; ++n)
                    acc[m][n] = mfma16f(fa[kk][m], fb[kk][n], acc[m][n]);
    }

    if (!QKV_EPI) {
        #pragma unroll
        for (int m = 0; m < 4; ++m)
            #pragma unroll
            for (int i = 0; i < 4; ++i) {
                const int r = row0 + wr * 64 + m * 16 + lg * 4 + i;
                #pragma unroll
                for (int n = 0; n < NF; ++n) {
                    const int c = col0 + wc * (NF * 16) + n * 16 + lc;
                    C[(size_t)r * N + c] = acc[m][n][i] + bias[c];
                }
            }
    } else {
        const int sec_blk = col0 >> 10;   // block-uniform: 0=q, 1=k, 2=v
        if (sec_blk == 2) {
            __syncthreads();
            #pragma unroll
            for (int m = 0; m < 4; ++m)
                #pragma unroll
                for (int n = 0; n < NF; ++n) {
                    const int lcol = wc * (NF * 16) + n * 16 + lc;
                    const int lrow = wr * 64 + m * 16 + lg * 4;
                    u16x4 o;
                    #pragma unroll
                    for (int i = 0; i < 4; ++i) o[i] = f32_f16(acc[m][n][i]);
                    *reinterpret_cast<u16x4*>(&lds[lcol * 136 + lrow]) = o;
                }
            __syncthreads();
            const int bb   = row0 >> 11;
            const int t0   = row0 & 2047;
            const int lcol = tid >> 1;
            const int th   = (tid & 1) * 64;
            const int ch   = (col0 - 2048) + lcol;
            ushort_t* dst = vt + ((size_t)(bb * NHEAD + (ch >> 6)) * HDIM + (ch & 63)) * CTXLEN
                            + t0 + th;
            #pragma unroll
            for (int j = 0; j < 8; ++j)
                *reinterpret_cast<u16x8*>(&dst[j * 8]) =
                    *reinterpret_cast<const u16x8*>(&lds[lcol * 136 + th + j * 8]);
        } else {
            #pragma unroll
            for (int m = 0; m < 4; ++m)
                #pragma unroll
                for (int i = 0; i < 4; ++i) {
                    const int r = row0 + wr * 64 + m * 16 + lg * 4 + i;
                    const int bb = r >> 11;
                    const int t  = r & 2047;
                    #pragma unroll
                    for (int n = 0; n < NF; ++n) {
                        const int cg = col0 + wc * (NF * 16) + n * 16 + lc;
                        const int ch = cg & 1023;
                        const int hh = ch >> 6;
                        const int d  = ch & 63;
                        const size_t off = (((size_t)(bb * NHEAD + hh)) * CTXLEN + t) * HDIM + d;
                        float v = acc[m][n][i];
                        if (sec_blk == 0) {
                            qf[off] = f32_f16(v * SCALE_LOG2);
                        } else {
                            kf[off] = f32_f16(v);
                        }
                    }
                }
        }
    }
}

// ---------------------------------------------------------------------------
// Flash causal attention v11: BARRIER-FREE 1-WAVE BLOCKS.
// Each old 4-wave unit becomes 4 independent 64-thread blocks; each stages
// its OWN K/V (KBLK=32, double-buffered, wave-private LDS 17KB -> 9/CU).
// Sync = own-wave `s_waitcnt vmcnt(0)` only; zero __syncthreads in the loop.
// Grid 10240: id -> w=id&3 (q quarter), bh=(id>>2)&31, u_off=79-(id>>7) (LPT).
// Redundant 4x K/V reads absorbed by L3 (16MB unique).
// ---------------------------------------------------------------------------
__global__ __launch_bounds__(64)
void attn_fwd11(const ushort_t* __restrict__ qf, const ushort_t* __restrict__ kf,
                const ushort_t* __restrict__ vt,
                ushort_t* __restrict__ py, float* __restrict__ pml,
                ushort_t* __restrict__ yb) {
    __shared__ ushort_t KH[2][2048];   // 32 k-rows x 64 d
    __shared__ ushort_t VT[2][2048];   // 64 d-rows x 32 t
    __shared__ ushort_t Ps[16][32];    // wave-private P bounce

    const int id    = blockIdx.x;
    const int wavq  = id & 3;                  // q-quarter within unit
    const int bh    = (id >> 2) & 31;
    const int u_off = 79 - (id >> 7);          // LPT: longest units first
    int qt, u;
    if (u_off < 8)       { qt = u_off;                          u = 0; }
    else if (u_off < 24) { const int t = u_off - 8;  qt = 8  + (t >> 1); u = t & 1; }
    else if (u_off < 48) { const int t = u_off - 24; const int q3 = t / 3; qt = 16 + q3; u = t - q3 * 3; }
    else                 { const int t = u_off - 48; qt = 24 + (t >> 2); u = t & 3; }
    const int total32 = 2 * qt + 2;            // unit k-range in 32-col tiles
    const int nu    = (qt >> 3) + 1;
    const int base  = total32 / nu, rem = total32 % nu;
    const int kb0   = u * base + (u < rem ? u : rem);
    int       len   = base + (u < rem ? 1 : 0);
    // skip trailing fully-masked 32-tile (k in [qt*64+32, qt*64+64), q < 32)
    if (kb0 + len == 2 * qt + 2 && wavq < 2) len -= 1;
    const int slot  = bh * 80 + u_off;

    const int lane = threadIdx.x;
    const int lc   = lane & 15;
    const int lg   = lane >> 4;

    const ushort_t* kfb = kf + (size_t)bh * CTXLEN * HDIM;
    const ushort_t* vtb = vt + (size_t)bh * HDIM * CTXLEN;

    auto stage = [&](int kb32, int buf) {
        const int koff = kb32 * 32;
        #pragma unroll
        for (int i = 0; i < 4; ++i) {
            const int c  = lane + i * 64;
            const int rk = c >> 3;
            const int sk = (c & 7) ^ (rk & 7);
            gload_lds16(kfb + (size_t)(koff + rk) * HDIM + sk * 8, &KH[buf][c * 8]);
            const int rv = c >> 2;
            const int sv = (c & 3) ^ (rv & 3);
            gload_lds16(vtb + (size_t)rv * CTXLEN + koff + sv * 8, &VT[buf][c * 8]);
        }
    };

    // Q fragments: q row = qt*64 + wavq*16 + lc  (q prescaled by 8*log2e)
    const size_t qrow = (size_t)bh * CTXLEN + qt * 64 + wavq * 16 + lc;
    f16x8 qfr[2];
    #pragma unroll
    for (int ds = 0; ds < 2; ++ds)
        qfr[ds] = *reinterpret_cast<const f16x8*>(&qf[qrow * HDIM + ds * 32 + lg * 8]);

    const f32x4 zero4 = {0.f, 0.f, 0.f, 0.f};
    f32x4 yacc[4];   // y^T: d = t*16+lg*4+i, q = lc
    #pragma unroll
    for (int t = 0; t < 4; ++t) yacc[t] = zero4;
    float m_i = -1e30f, l_i = 0.f;

    stage(kb0, 0);

    for (int s = 0; s < len; ++s) {
        const int kb32 = kb0 + s;
        const int cur  = s & 1;

        // own-wave wait: buffer `cur` DMA complete (no barrier)
        asm volatile("s_waitcnt vmcnt(0)" ::: "memory");

        // K fragments (swizzled): rows 0..31
        f16x8 kfr[2][2];
        #pragma unroll
        for (int tc = 0; tc < 2; ++tc) {
            const int rk = tc * 16 + lc;
            #pragma unroll
            for (int ds = 0; ds < 2; ++ds) {
                const int a = rk * 64 + (((ds * 4 + lg) ^ (rk & 7)) * 8);
                kfr[tc][ds] = *reinterpret_cast<const f16x8*>(&KH[cur][a]);
            }
        }
        // V^T fragments (swizzled): rows 0..63 (d), 32 t-cols
        f16x8 vf[4];
        #pragma unroll
        for (int t = 0; t < 4; ++t) {
            const int rv = t * 16 + lc;
            vf[t] = *reinterpret_cast<const f16x8*>(&VT[cur][rv * 32 + ((lg ^ (rv & 3)) * 8)]);
        }

        // prefetch next tile into the other buffer (DMA overlaps compute)
        if (s + 1 < len) stage(kb32 + 1, cur ^ 1);

        // S^T = K Q^T : D[k = tc*16+lg*4+i][q = lc] (log2 units)
        f32x4 sacc[2];
        #pragma unroll
        for (int tc = 0; tc < 2; ++tc) sacc[tc] = zero4;
        __builtin_amdgcn_s_setprio(1);
        #pragma unroll
        for (int tc = 0; tc < 2; ++tc)
            #pragma unroll
            for (int ds = 0; ds < 2; ++ds)
                sacc[tc] = mfma16f(kfr[tc][ds], qfr[ds], sacc[tc]);
        __builtin_amdgcn_s_setprio(0);

        float p[2][4];
        #pragma unroll
        for (int tc = 0; tc < 2; ++tc)
            #pragma unroll
            for (int i = 0; i < 4; ++i)
                p[tc][i] = sacc[tc][i];
        if (kb32 >= 2 * qt) {   // diagonal 64-block: causal mask
            const int q_loc = wavq * 16 + lc;
            #pragma unroll
            for (int tc = 0; tc < 2; ++tc)
                #pragma unroll
                for (int i = 0; i < 4; ++i) {
                    const int k_loc = (kb32 & 1) * 32 + tc * 16 + lg * 4 + i;
                    if (k_loc > q_loc) p[tc][i] = -1e30f;
                }
        }
        float mx = p[0][0];
        #pragma unroll
        for (int tc = 0; tc < 2; ++tc)
            #pragma unroll
            for (int i = 0; i < 4; ++i) mx = fmaxf(mx, p[tc][i]);
        mx = fmaxf(mx, __shfl_xor(mx, 16));
        mx = fmaxf(mx, __shfl_xor(mx, 32));

        if (__all(mx <= m_i + 8.0f)) {
            float psum = 0.f;
            #pragma unroll
            for (int tc = 0; tc < 2; ++tc)
                #pragma unroll
                for (int i = 0; i < 4; ++i) {
                    const float e = fast_exp2(p[tc][i] - m_i);
                    p[tc][i] = e;
                    psum += e;
                }
            psum += __shfl_xor(psum, 16);
            psum += __shfl_xor(psum, 32);
            l_i += psum;
        } else {
            const float mnew = fmaxf(m_i, mx);
            const float corr = fast_exp2(m_i - mnew);
            float psum = 0.f;
            #pragma unroll
            for (int tc = 0; tc < 2; ++tc)
                #pragma unroll
                for (int i = 0; i < 4; ++i) {
                    const float e = fast_exp2(p[tc][i] - mnew);
                    p[tc][i] = e;
                    psum += e;
                }
            psum += __shfl_xor(psum, 16);
            psum += __shfl_xor(psum, 32);
            l_i = l_i * corr + psum;
            m_i = mnew;
            #pragma unroll
            for (int t = 0; t < 4; ++t) yacc[t] *= corr;
        }

        // P -> Ps (wave-private, 32-col row, XOR chunk swizzle)
        #pragma unroll
        for (int tc = 0; tc < 2; ++tc) {
            const int eb = tc * 16 + lg * 4;                    // 0..28
            const int se = ((((eb >> 3) ^ (lc & 3)) << 3) | (eb & 7));
            u16x4 pk;
            #pragma unroll
            for (int i = 0; i < 4; ++i) pk[i] = f32_f16(p[tc][i]);
            *reinterpret_cast<u16x4*>(&Ps[lc][se]) = pk;
        }
        const f16x8 pa = *reinterpret_cast<const f16x8*>(&Ps[lc][(lg ^ (lc & 3)) * 8]);

        // y^T += V^T P  (k = 32)
        __builtin_amdgcn_s_setprio(1);
        #pragma unroll
        for (int t = 0; t < 4; ++t)
            yacc[t] = mfma16f(vf[t], pa, yacc[t]);
        __builtin_amdgcn_s_setprio(0);
    }

    const int row = wavq * 16 + lc;
    if (nu == 1) {
        const float inv = 1.0f / l_i;
        const int b = bh >> 4, h = bh & 15;
        ushort_t* dst = yb + (size_t)(b * CTXLEN + qt * 64 + row) * DMODEL + h * HDIM;
        #pragma unroll
        for (int t = 0; t < 4; ++t) {
            u16x4 o;
            #pragma unroll
            for (int i = 0; i < 4; ++i) o[i] = f32_f16(yacc[t][i] * inv);
            *reinterpret_cast<u16x4*>(&dst[t * 16 + lg * 4]) = o;
        }
    } else {
        ushort_t* prow = py + ((size_t)slot * 64 + row) * 64;
        #pragma unroll
        for (int t = 0; t < 4; ++t) {
            u16x4 o;
            #pragma unroll
            for (int i = 0; i < 4; ++i) o[i] = f32_f16(yacc[t][i]);
            *reinterpret_cast<u16x4*>(&prow[t * 16 + lg * 4]) = o;
        }
        if (lg == 0) {
            pml[(size_t)slot * 128 + row]      = m_i;
            pml[(size_t)slot * 128 + 64 + row] = l_i;
        }
    }
}

// ---------------------------------------------------------------------------
// Merge split-KV partials for qt >= 8 only. Grid (24, 32): x = qt-8, y = bh.
// ---------------------------------------------------------------------------
__global__ __launch_bounds__(256)
void merge_attn(const ushort_t* __restrict__ py, const float* __restrict__ pml,
                ushort_t* __restrict__ yb) {
    const int qt  = 8 + blockIdx.x;
    const int bh  = blockIdx.y;
    const int b   = bh >> 4;
    const int h   = bh & 15;
    const int tid = threadIdx.x;
    const int row = tid >> 2;
    const int d0  = (tid & 3) * 16;

    const int nu    = (qt >> 3) + 1;
    const int sbase = bh * 80 + unit_off(qt);

    float mu[4], lu[4];
    float M = -1e30f;
    #pragma unroll
    for (int u = 0; u < 4; ++u) {
        if (u < nu) {
            mu[u] = pml[(size_t)(sbase + u) * 128 + row];
            lu[u] = pml[(size_t)(sbase + u) * 128 + 64 + row];
            M = fmaxf(M, mu[u]);
        } else { mu[u] = -1e30f; lu[u] = 0.f; }
    }
    float w[4], ltot = 0.f;
    #pragma unroll
    for (int u = 0; u < 4; ++u) {
        w[u] = (u < nu) ? fast_exp2(mu[u] - M) : 0.f;
        ltot += w[u] * lu[u];
    }

    float y[16];
    #pragma unroll
    for (int j = 0; j < 16; ++j) y[j] = 0.f;
    #pragma unroll
    for (int u = 0; u < 4; ++u) {
        if (u < nu) {
            const ushort_t* pr = py + ((size_t)(sbase + u) * 64 + row) * 64 + d0;
            const u16x8 a = *reinterpret_cast<const u16x8*>(&pr[0]);
            const u16x8 c = *reinterpret_cast<const u16x8*>(&pr[8]);
            #pragma unroll
            for (int j = 0; j < 8; ++j) {
                y[j]     += w[u] * f16_f32(a[j]);
                y[8 + j] += w[u] * f16_f32(c[j]);
            }
        }
    }
    const float inv = 1.0f / ltot;
    ushort_t* dst = yb + (size_t)(b * CTXLEN + qt * 64 + row) * DMODEL + h * HDIM + d0;
    u16x8 o0, o1;
    #pragma unroll
    for (int j = 0; j < 8; ++j) {
        o0[j] = f32_f16(y[j] * inv);
        o1[j] = f32_f16(y[8 + j] * inv);
    }
    *reinterpret_cast<u16x8*>(&dst[0]) = o0;
    *reinterpret_cast<u16x8*>(&dst[8]) = o1;
}

// ---------------------------------------------------------------------------
extern "C" void kernel_launch(void* const* d_in, const int* in_sizes, int n_in,
                              void* d_out, int out_size, void* d_ws, size_t ws_size,
                              hipStream_t stream) {
    const float* x      = (const float*)d_in[0];
    const float* w_qkv  = (const float*)d_in[1];
    const float* w_proj = (const float*)d_in[2];
    const float* b_proj = (const float*)d_in[3];
    float* out = (float*)d_out;

    // ws layout (bytes):
    //   wqf f16 [3072,1024]                 @ 0          (6,291,456)
    //   wpf f16 [1024,1024]                 @ 6291456    (2,097,152)
    //   xf  f16 [4096,1024] | yb f16 reuse  @ 8388608    (8,388,608)
    //   qf  f16 [32][2048][64]              @ 16777216   (8,388,608)
    //   kf  f16 [32][2048][64]              @ 25165824   (8,388,608)
    //   (gap)                               @ 33554432   (8,388,608)
    //   vt  f16 [32][64][2048]              @ 41943040   (8,388,608)
    //   py  f16 [2560][64][64]              @ 50331648   (20,971,520)
    //   pml f32 [2560][128]                 @ 71303168   ( 1,310,720)
    char* ws = (char*)d_ws;
    ushort_t* wqf = (ushort_t*)(ws);
    ushort_t* wpf = (ushort_t*)(ws + 6291456);
    ushort_t* xf  = (ushort_t*)(ws + 8388608);
    ushort_t* qf  = (ushort_t*)(ws + 16777216);
    ushort_t* kf  = (ushort_t*)(ws + 25165824);
    ushort_t* vt  = (ushort_t*)(ws + 41943040);
    ushort_t* py  = (ushort_t*)(ws + 50331648);
    float*    pml = (float*)   (ws + 71303168);
    ushort_t* yb  = xf;   // reused after qkv GEMM consumed xf

    const dim3 blk(256);

    // one fused convert launch: x, w_qkv, w_proj -> f16
    conv3_f32_f16<<<dim3(2048), blk, 0, stream>>>(
        x, xf, M_TOTAL * DMODEL / 4,
        w_qkv, wqf, 3 * DMODEL * DMODEL / 4,
        w_proj, wpf, DMODEL * DMODEL / 4);

    // qkv = x @ w_qkv^T (N=3072, BK=64); epilogue scatters q (prescaled) / k
    // and writes v TRANSPOSED (vt) directly
    gemm_f16_nt<128, true><<<dim3(3 * DMODEL / 128, M_TOTAL / 128), blk, 0, stream>>>(
        xf, wqf, nullptr, nullptr, qf, kf, vt, M_TOTAL, 3 * DMODEL, DMODEL);

    // barrier-free 1-wave split-KV attention units + merge
    attn_fwd11<<<dim3(10240), dim3(64), 0, stream>>>(qf, kf, vt, py, pml, yb);
    merge_attn<<<dim3(24, 32), blk, 0, stream>>>(py, pml, yb);

    // out = y @ w_proj^T + b  — BN=64 tiles, BK=64 -> 512 blocks (2/CU)
    gemm_f16_nt<64, false><<<dim3(DMODEL / 64, M_TOTAL / 128), blk, 0, stream>>>(
        yb, wpf, b_proj, out, nullptr, nullptr, nullptr, M_TOTAL, DMODEL, DMODEL);
}

// Round 23
// 105.333 us; speedup vs baseline: 1.4758x; 1.4758x over previous
//
#include <hip/hip_runtime.h>
#include <hip/hip_bf16.h>

#define DMODEL 1024
#define NHEAD 16
#define HDIM 64
#define CTXLEN 2048
#define BATCH 2
#define M_TOTAL (BATCH * CTXLEN)   // 4096

typedef unsigned short ushort_t;
typedef __attribute__((ext_vector_type(8))) _Float16 f16x8;
typedef __attribute__((ext_vector_type(8))) unsigned short u16x8;
typedef __attribute__((ext_vector_type(4))) float f32x4;
typedef __attribute__((ext_vector_type(4))) unsigned short u16x4;

#define SCALE_LOG2 11.5415603271f   // 8 * log2(e) — folded into q at GEMM epilogue

__device__ __forceinline__ unsigned short f32_f16(float f) {
    return __builtin_bit_cast(unsigned short, (_Float16)f);
}
__device__ __forceinline__ float f16_f32(unsigned short h) {
    return (float)__builtin_bit_cast(_Float16, h);
}
__device__ __forceinline__ float fast_exp2(float x) {
    return __builtin_amdgcn_exp2f(x);
}
__device__ __forceinline__ f32x4 mfma16f(f16x8 a, f16x8 b, f32x4 c) {
    return __builtin_amdgcn_mfma_f32_16x16x32_f16(a, b, c, 0, 0, 0);
}
__device__ __forceinline__ void gload_lds16(const ushort_t* g, ushort_t* l) {
    __builtin_amdgcn_global_load_lds(
        (const __attribute__((address_space(1))) void*)g,
        (__attribute__((address_space(3))) void*)l, 16, 0, 0);
}
// units per q-tile: nu = qt/8+1; slot offset of first unit of qt within a bh
__device__ __forceinline__ int unit_off(int qt) {
    if (qt < 8)  return qt;
    if (qt < 16) return 8 + (qt - 8) * 2;
    if (qt < 24) return 24 + (qt - 16) * 3;
    return 48 + (qt - 24) * 4;
}

// ---------------------------------------------------------------------------
// fused f32 -> f16 convert for 3 arrays (one launch)
// ---------------------------------------------------------------------------
__global__ __launch_bounds__(256)
void conv3_f32_f16(const float* __restrict__ a, ushort_t* __restrict__ da, int na4,
                   const float* __restrict__ b, ushort_t* __restrict__ db, int nb4,
                   const float* __restrict__ c, ushort_t* __restrict__ dc, int nc4) {
    const int n = na4 + nb4 + nc4;
    for (int i = blockIdx.x * blockDim.x + threadIdx.x; i < n;
         i += gridDim.x * blockDim.x) {
        const float* s; ushort_t* d; int j = i;
        if (j < na4) { s = a; d = da; }
        else if (j - na4 < nb4) { j -= na4; s = b; d = db; }
        else { j -= na4 + nb4; s = c; d = dc; }
        const float4 v = reinterpret_cast<const float4*>(s)[j];
        u16x4 o;
        o[0] = f32_f16(v.x); o[1] = f32_f16(v.y);
        o[2] = f32_f16(v.z); o[3] = f32_f16(v.w);
        reinterpret_cast<u16x4*>(d)[j] = o;
    }
}

// ---------------------------------------------------------------------------
// fp16 MFMA GEMM (NT): C = A·B^T. BM=128, BN template (128 or 64), BK=64.
// XCD-aware bijective block swizzle. QKV_EPI: sec block-uniform;
//   sec 0/1: scatter q (prescaled) / k.  sec 2: V-transpose fused via LDS.
// ---------------------------------------------------------------------------
template<int BN, bool QKV_EPI>
__global__ __launch_bounds__(256)
void gemm_f16_nt(const ushort_t* __restrict__ A, const ushort_t* __restrict__ B,
                 const float* __restrict__ bias, float* __restrict__ C,
                 ushort_t* __restrict__ qf, ushort_t* __restrict__ kf,
                 ushort_t* __restrict__ vt,
                 int M, int N, int K) {
    constexpr int NF = BN / 32;
    constexpr int BOFF = 8192;
    constexpr int BCHUNK = BN * 8;
    constexpr int LDSZ = QKV_EPI ? 17408 : (BOFF + BN * 64);
    __shared__ ushort_t lds[LDSZ];

    int bx, by;
    {
        const int gx  = gridDim.x;
        const int nwg = gx * (int)gridDim.y;
        const int cpx = nwg >> 3;
        int flat = (int)blockIdx.y * gx + (int)blockIdx.x;
        flat = (flat & 7) * cpx + (flat >> 3);
        bx = flat % gx;
        by = flat / gx;
    }

    const int tid  = threadIdx.x;
    const int lane = tid & 63;
    const int wave = tid >> 6;
    const int lc   = lane & 15;
    const int lg   = lane >> 4;
    const int wr   = wave >> 1;
    const int wc   = wave & 1;
    const int row0 = by * 128;
    const int col0 = bx * BN;

    int aoff[4][2], boff[NF][2];
    #pragma unroll
    for (int m = 0; m < 4; ++m) {
        const int ra = wr * 64 + m * 16 + lc;
        #pragma unroll
        for (int kk = 0; kk < 2; ++kk)
            aoff[m][kk] = ra * 64 + (((kk * 4 + lg) ^ (ra & 7)) * 8);
    }
    #pragma unroll
    for (int n = 0; n < NF; ++n) {
        const int rb = wc * (NF * 16) + n * 16 + lc;
        #pragma unroll
        for (int kk = 0; kk < 2; ++kk)
            boff[n][kk] = rb * 64 + (((kk * 4 + lg) ^ (rb & 7)) * 8);
    }

    f32x4 acc[4][NF];
    const f32x4 zero4 = {0.f, 0.f, 0.f, 0.f};
    #pragma unroll
    for (int m = 0; m < 4; ++m)
        #pragma unroll
        for (int n = 0; n < NF; ++n) acc[m][n] = zero4;

    const int NT = K >> 6;

    auto stage = [&](int kt) {
        const int ko = kt * 64;
        #pragma unroll
        for (int i = 0; i < 4; ++i) {
            const int c  = tid + i * 256;
            const int r  = c >> 3;
            const int sg = (c & 7) ^ (r & 7);
            gload_lds16(A + (size_t)(row0 + r) * K + ko + sg * 8, &lds[c * 8]);
        }
        #pragma unroll
        for (int i = 0; i < BCHUNK / 256; ++i) {
            const int c  = tid + i * 256;
            const int r  = c >> 3;
            const int sg = (c & 7) ^ (r & 7);
            gload_lds16(B + (size_t)(col0 + r) * K + ko + sg * 8, &lds[BOFF + c * 8]);
        }
    };

    stage(0);
    for (int kt = 0; kt < NT; ++kt) {
        __syncthreads();
        f16x8 fa[2][4], fb[2][NF];
        #pragma unroll
        for (int kk = 0; kk < 2; ++kk) {
            #pragma unroll
            for (int m = 0; m < 4; ++m)
                fa[kk][m] = *reinterpret_cast<const f16x8*>(&lds[aoff[m][kk]]);
            #pragma unroll
            for (int n = 0; n < NF; ++n)
                fb[kk][n] = *reinterpret_cast<const f16x8*>(&lds[BOFF + boff[n][kk]]);
        }
        __syncthreads();
        if (kt + 1 < NT) stage(kt + 1);
        #pragma unroll
        for (int kk = 0; kk < 2; ++kk)
            #pragma unroll
            for (int m = 0; m < 4; ++m)
                #pragma unroll
                for (int n = 0; n < NF; ++n)
                    acc[m][n] = mfma16f(fa[kk][m], fb[kk][n], acc[m][n]);
    }

    if (!QKV_EPI) {
        #pragma unroll
        for (int m = 0; m < 4; ++m)
            #pragma unroll
            for (int i = 0; i < 4; ++i) {
                const int r = row0 + wr * 64 + m * 16 + lg * 4 + i;
                #pragma unroll
                for (int n = 0; n < NF; ++n) {
                    const int c = col0 + wc * (NF * 16) + n * 16 + lc;
                    C[(size_t)r * N + c] = acc[m][n][i] + bias[c];
                }
            }
    } else {
        const int sec_blk = col0 >> 10;   // block-uniform: 0=q, 1=k, 2=v
        if (sec_blk == 2) {
            __syncthreads();
            #pragma unroll
            for (int m = 0; m < 4; ++m)
                #pragma unroll
                for (int n = 0; n < NF; ++n) {
                    const int lcol = wc * (NF * 16) + n * 16 + lc;
                    const int lrow = wr * 64 + m * 16 + lg * 4;
                    u16x4 o;
                    #pragma unroll
                    for (int i = 0; i < 4; ++i) o[i] = f32_f16(acc[m][n][i]);
                    *reinterpret_cast<u16x4*>(&lds[lcol * 136 + lrow]) = o;
                }
            __syncthreads();
            const int bb   = row0 >> 11;
            const int t0   = row0 & 2047;
            const int lcol = tid >> 1;
            const int th   = (tid & 1) * 64;
            const int ch   = (col0 - 2048) + lcol;
            ushort_t* dst = vt + ((size_t)(bb * NHEAD + (ch >> 6)) * HDIM + (ch & 63)) * CTXLEN
                            + t0 + th;
            #pragma unroll
            for (int j = 0; j < 8; ++j)
                *reinterpret_cast<u16x8*>(&dst[j * 8]) =
                    *reinterpret_cast<const u16x8*>(&lds[lcol * 136 + th + j * 8]);
        } else {
            #pragma unroll
            for (int m = 0; m < 4; ++m)
                #pragma unroll
                for (int i = 0; i < 4; ++i) {
                    const int r = row0 + wr * 64 + m * 16 + lg * 4 + i;
                    const int bb = r >> 11;
                    const int t  = r & 2047;
                    #pragma unroll
                    for (int n = 0; n < NF; ++n) {
                        const int cg = col0 + wc * (NF * 16) + n * 16 + lc;
                        const int ch = cg & 1023;
                        const int hh = ch >> 6;
                        const int d  = ch & 63;
                        const size_t off = (((size_t)(bb * NHEAD + hh)) * CTXLEN + t) * HDIM + d;
                        float v = acc[m][n][i];
                        if (sec_blk == 0) {
                            qf[off] = f32_f16(v * SCALE_LOG2);
                        } else {
                            kf[off] = f32_f16(v);
                        }
                    }
                }
        }
    }
}

// ---------------------------------------------------------------------------
// Flash causal attention: split-KV v7 (QBLK=64, units <=8 steps, grid 2560,
// LPT order) + defer-max + prescaled q. nu==1 units (qt<8) write yb directly.
// (proven at ~51 us across 4 independent runs)
// ---------------------------------------------------------------------------
__global__ __launch_bounds__(256)
void attn_fwd7(const ushort_t* __restrict__ qf, const ushort_t* __restrict__ kf,
               const ushort_t* __restrict__ vt,
               ushort_t* __restrict__ py, float* __restrict__ pml,
               ushort_t* __restrict__ yb) {
    __shared__ ushort_t KH[2][4096];
    __shared__ ushort_t VT[2][4096];
    __shared__ ushort_t Ps[4][16][64];

    const int id    = blockIdx.x;
    const int bh    = id & 31;
    const int u_off = 79 - (id >> 5);          // LPT: longest units first
    int qt, u;
    if (u_off < 8)       { qt = u_off;                          u = 0; }
    else if (u_off < 24) { const int t = u_off - 8;  qt = 8  + (t >> 1); u = t & 1; }
    else if (u_off < 48) { const int t = u_off - 24; const int q3 = t / 3; qt = 16 + q3; u = t - q3 * 3; }
    else                 { const int t = u_off - 48; qt = 24 + (t >> 2); u = t & 3; }
    const int total = qt + 1;
    const int nu    = (qt >> 3) + 1;
    const int base  = total / nu, rem = total % nu;
    const int kb0   = u * base + (u < rem ? u : rem);
    const int len   = base + (u < rem ? 1 : 0);
    const int slot  = bh * 80 + u_off;

    const int tid  = threadIdx.x;
    const int wave = tid >> 6;
    const int lane = tid & 63;
    const int lc   = lane & 15;
    const int lg   = lane >> 4;

    const ushort_t* kfb = kf + (size_t)bh * CTXLEN * HDIM;
    const ushort_t* vtb = vt + (size_t)bh * HDIM * CTXLEN;

    const int cA = tid, cB = 256 + tid;
    const int rA = cA >> 3, sgA = (cA & 7) ^ (rA & 7);
    const int rB = cB >> 3, sgB = (cB & 7) ^ (rB & 7);

    auto stage = [&](int kb, int buf) {
        const size_t koff = (size_t)(kb * 64);
        gload_lds16(kfb + (koff + rA) * HDIM + sgA * 8, &KH[buf][cA * 8]);
        gload_lds16(kfb + (koff + rB) * HDIM + sgB * 8, &KH[buf][cB * 8]);
        gload_lds16(vtb + (size_t)rA * CTXLEN + kb * 64 + sgA * 8, &VT[buf][cA * 8]);
        gload_lds16(vtb + (size_t)rB * CTXLEN + kb * 64 + sgB * 8, &VT[buf][cB * 8]);
    };

    // Q fragments: q row = qt*64 + wave*16 + lc  (q prescaled by 8*log2e)
    const size_t qrow = (size_t)bh * CTXLEN + qt * 64 + wave * 16 + lc;
    f16x8 qfr[2];
    #pragma unroll
    for (int ds = 0; ds < 2; ++ds)
        qfr[ds] = *reinterpret_cast<const f16x8*>(&qf[qrow * HDIM + ds * 32 + lg * 8]);

    const f32x4 zero4 = {0.f, 0.f, 0.f, 0.f};
    f32x4 yacc[4];   // y^T: d = t*16+lg*4+i, q = lc
    #pragma unroll
    for (int t = 0; t < 4; ++t) yacc[t] = zero4;
    float m_i = -1e30f, l_i = 0.f;

    stage(kb0, 0);
    __syncthreads();

    int cur = 0;
    for (int s = 0; s < len; ++s) {
        const int kb = kb0 + s;
        if (s + 1 < len) stage(kb + 1, cur ^ 1);

        f16x8 kfr[4][2];
        #pragma unroll
        for (int tc = 0; tc < 4; ++tc) {
            const int rk = tc * 16 + lc;
            #pragma unroll
            for (int ds = 0; ds < 2; ++ds) {
                const int a = rk * 64 + (((ds * 4 + lg) ^ (rk & 7)) * 8);
                kfr[tc][ds] = *reinterpret_cast<const f16x8*>(&KH[cur][a]);
            }
        }
        f16x8 vf[4][2];
        #pragma unroll
        for (int t = 0; t < 4; ++t) {
            const int rv = t * 16 + lc;
            #pragma unroll
            for (int ks = 0; ks < 2; ++ks) {
                const int a = rv * 64 + (((ks * 4 + lg) ^ (rv & 7)) * 8);
                vf[t][ks] = *reinterpret_cast<const f16x8*>(&VT[cur][a]);
            }
        }

        f32x4 sacc[4];
        #pragma unroll
        for (int tc = 0; tc < 4; ++tc) sacc[tc] = zero4;
        __builtin_amdgcn_s_setprio(1);
        #pragma unroll
        for (int tc = 0; tc < 4; ++tc)
            #pragma unroll
            for (int ds = 0; ds < 2; ++ds)
                sacc[tc] = mfma16f(kfr[tc][ds], qfr[ds], sacc[tc]);
        __builtin_amdgcn_s_setprio(0);

        float p[4][4];
        #pragma unroll
        for (int tc = 0; tc < 4; ++tc)
            #pragma unroll
            for (int i = 0; i < 4; ++i)
                p[tc][i] = sacc[tc][i];
        if (kb == qt) {   // diagonal tile only: causal mask (wave-uniform branch)
            const int q_loc = wave * 16 + lc;
            #pragma unroll
            for (int tc = 0; tc < 4; ++tc)
                #pragma unroll
                for (int i = 0; i < 4; ++i)
                    if ((tc * 16 + lg * 4 + i) > q_loc) p[tc][i] = -1e30f;
        }
        float mx = p[0][0];
        #pragma unroll
        for (int tc = 0; tc < 4; ++tc)
            #pragma unroll
            for (int i = 0; i < 4; ++i) mx = fmaxf(mx, p[tc][i]);
        mx = fmaxf(mx, __shfl_xor(mx, 16));
        mx = fmaxf(mx, __shfl_xor(mx, 32));

        if (__all(mx <= m_i + 8.0f)) {
            // defer-max: keep m_i, skip corr/rescale (p <= 2^8, f16-safe)
            float psum = 0.f;
            #pragma unroll
            for (int tc = 0; tc < 4; ++tc)
                #pragma unroll
                for (int i = 0; i < 4; ++i) {
                    const float e = fast_exp2(p[tc][i] - m_i);
                    p[tc][i] = e;
                    psum += e;
                }
            psum += __shfl_xor(psum, 16);
            psum += __shfl_xor(psum, 32);
            l_i += psum;
        } else {
            const float mnew = fmaxf(m_i, mx);
            const float corr = fast_exp2(m_i - mnew);
            float psum = 0.f;
            #pragma unroll
            for (int tc = 0; tc < 4; ++tc)
                #pragma unroll
                for (int i = 0; i < 4; ++i) {
                    const float e = fast_exp2(p[tc][i] - mnew);
                    p[tc][i] = e;
                    psum += e;
                }
            psum += __shfl_xor(psum, 16);
            psum += __shfl_xor(psum, 32);
            l_i = l_i * corr + psum;
            m_i = mnew;
            #pragma unroll
            for (int t = 0; t < 4; ++t) yacc[t] *= corr;
        }

        // P -> Ps (wave-private, swizzled, u16x4 chunks)
        #pragma unroll
        for (int tc = 0; tc < 4; ++tc) {
            const int eb = tc * 16 + lg * 4;
            const int se = ((((eb >> 3) ^ (lc & 7)) << 3) | (eb & 7));
            u16x4 pk;
            #pragma unroll
            for (int i = 0; i < 4; ++i) pk[i] = f32_f16(p[tc][i]);
            *reinterpret_cast<u16x4*>(&Ps[wave][lc][se]) = pk;
        }
        f16x8 pa[2];
        #pragma unroll
        for (int ks = 0; ks < 2; ++ks) {
            const int sl = ((ks * 4 + lg) ^ (lc & 7)) << 3;
            pa[ks] = *reinterpret_cast<const f16x8*>(&Ps[wave][lc][sl]);
        }
        // y^T += V^T P
        __builtin_amdgcn_s_setprio(1);
        #pragma unroll
        for (int t = 0; t < 4; ++t)
            #pragma unroll
            for (int ks = 0; ks < 2; ++ks)
                yacc[t] = mfma16f(vf[t][ks], pa[ks], yacc[t]);
        __builtin_amdgcn_s_setprio(0);

        __syncthreads();
        cur ^= 1;
    }

    const int row = wave * 16 + lc;
    if (nu == 1) {
        // single-unit q-tile (qt < 8): normalize and write final y directly
        const float inv = 1.0f / l_i;
        const int b = bh >> 4, h = bh & 15;
        ushort_t* dst = yb + (size_t)(b * CTXLEN + qt * 64 + row) * DMODEL + h * HDIM;
        #pragma unroll
        for (int t = 0; t < 4; ++t) {
            u16x4 o;
            #pragma unroll
            for (int i = 0; i < 4; ++i) o[i] = f32_f16(yacc[t][i] * inv);
            *reinterpret_cast<u16x4*>(&dst[t * 16 + lg * 4]) = o;
        }
    } else {
        // partial epilogue: unnormalized y (f16) + m,l (f32)
        ushort_t* prow = py + ((size_t)slot * 64 + row) * 64;
        #pragma unroll
        for (int t = 0; t < 4; ++t) {
            u16x4 o;
            #pragma unroll
            for (int i = 0; i < 4; ++i) o[i] = f32_f16(yacc[t][i]);
            *reinterpret_cast<u16x4*>(&prow[t * 16 + lg * 4]) = o;
        }
        if (lg == 0) {
            pml[(size_t)slot * 128 + row]      = m_i;
            pml[(size_t)slot * 128 + 64 + row] = l_i;
        }
    }
}

// ---------------------------------------------------------------------------
// Merge split-KV partials for qt >= 8 only. Grid (24, 32): x = qt-8, y = bh.
// ---------------------------------------------------------------------------
__global__ __launch_bounds__(256)
void merge_attn(const ushort_t* __restrict__ py, const float* __restrict__ pml,
                ushort_t* __restrict__ yb) {
    const int qt  = 8 + blockIdx.x;
    const int bh  = blockIdx.y;
    const int b   = bh >> 4;
    const int h   = bh & 15;
    const int tid = threadIdx.x;
    const int row = tid >> 2;
    const int d0  = (tid & 3) * 16;

    const int nu    = (qt >> 3) + 1;
    const int sbase = bh * 80 + unit_off(qt);

    float mu[4], lu[4];
    float M = -1e30f;
    #pragma unroll
    for (int u = 0; u < 4; ++u) {
        if (u < nu) {
            mu[u] = pml[(size_t)(sbase + u) * 128 + row];
            lu[u] = pml[(size_t)(sbase + u) * 128 + 64 + row];
            M = fmaxf(M, mu[u]);
        } else { mu[u] = -1e30f; lu[u] = 0.f; }
    }
    float w[4], ltot = 0.f;
    #pragma unroll
    for (int u = 0; u < 4; ++u) {
        w[u] = (u < nu) ? fast_exp2(mu[u] - M) : 0.f;
        ltot += w[u] * lu[u];
    }

    float y[16];
    #pragma unroll
    for (int j = 0; j < 16; ++j) y[j] = 0.f;
    #pragma unroll
    for (int u = 0; u < 4; ++u) {
        if (u < nu) {
            const ushort_t* pr = py + ((size_t)(sbase + u) * 64 + row) * 64 + d0;
            const u16x8 a = *reinterpret_cast<const u16x8*>(&pr[0]);
            const u16x8 c = *reinterpret_cast<const u16x8*>(&pr[8]);
            #pragma unroll
            for (int j = 0; j < 8; ++j) {
                y[j]     += w[u] * f16_f32(a[j]);
                y[8 + j] += w[u] * f16_f32(c[j]);
            }
        }
    }
    const float inv = 1.0f / ltot;
    ushort_t* dst = yb + (size_t)(b * CTXLEN + qt * 64 + row) * DMODEL + h * HDIM + d0;
    u16x8 o0, o1;
    #pragma unroll
    for (int j = 0; j < 8; ++j) {
        o0[j] = f32_f16(y[j] * inv);
        o1[j] = f32_f16(y[8 + j] * inv);
    }
    *reinterpret_cast<u16x8*>(&dst[0]) = o0;
    *reinterpret_cast<u16x8*>(&dst[8]) = o1;
}

// ---------------------------------------------------------------------------
extern "C" void kernel_launch(void* const* d_in, const int* in_sizes, int n_in,
                              void* d_out, int out_size, void* d_ws, size_t ws_size,
                              hipStream_t stream) {
    const float* x      = (const float*)d_in[0];
    const float* w_qkv  = (const float*)d_in[1];
    const float* w_proj = (const float*)d_in[2];
    const float* b_proj = (const float*)d_in[3];
    float* out = (float*)d_out;

    // ws layout (bytes):
    //   wqf f16 [3072,1024]                 @ 0          (6,291,456)
    //   wpf f16 [1024,1024]                 @ 6291456    (2,097,152)
    //   xf  f16 [4096,1024] | yb f16 reuse  @ 8388608    (8,388,608)
    //   qf  f16 [32][2048][64]              @ 16777216   (8,388,608)
    //   kf  f16 [32][2048][64]              @ 25165824   (8,388,608)
    //   (gap)                               @ 33554432   (8,388,608)
    //   vt  f16 [32][64][2048]              @ 41943040   (8,388,608)
    //   py  f16 [2560][64][64]              @ 50331648   (20,971,520)
    //   pml f32 [2560][128]                 @ 71303168   ( 1,310,720)
    char* ws = (char*)d_ws;
    ushort_t* wqf = (ushort_t*)(ws);
    ushort_t* wpf = (ushort_t*)(ws + 6291456);
    ushort_t* xf  = (ushort_t*)(ws + 8388608);
    ushort_t* qf  = (ushort_t*)(ws + 16777216);
    ushort_t* kf  = (ushort_t*)(ws + 25165824);
    ushort_t* vt  = (ushort_t*)(ws + 41943040);
    ushort_t* py  = (ushort_t*)(ws + 50331648);
    float*    pml = (float*)   (ws + 71303168);
    ushort_t* yb  = xf;   // reused after qkv GEMM consumed xf

    const dim3 blk(256);

    // one fused convert launch: x, w_qkv, w_proj -> f16
    conv3_f32_f16<<<dim3(2048), blk, 0, stream>>>(
        x, xf, M_TOTAL * DMODEL / 4,
        w_qkv, wqf, 3 * DMODEL * DMODEL / 4,
        w_proj, wpf, DMODEL * DMODEL / 4);

    // qkv = x @ w_qkv^T (N=3072, BK=64); epilogue scatters q (prescaled) / k
    // and writes v TRANSPOSED (vt) directly — no separate transpose kernel
    gemm_f16_nt<128, true><<<dim3(3 * DMODEL / 128, M_TOTAL / 128), blk, 0, stream>>>(
        xf, wqf, nullptr, nullptr, qf, kf, vt, M_TOTAL, 3 * DMODEL, DMODEL);

    // split-KV attention units (LPT order; qt<8 write yb directly) + merge
    attn_fwd7<<<dim3(2560), blk, 0, stream>>>(qf, kf, vt, py, pml, yb);
    merge_attn<<<dim3(24, 32), blk, 0, stream>>>(py, pml, yb);

    // out = y @ w_proj^T + b  — BN=64 tiles, BK=64 -> 512 blocks (2/CU)
    gemm_f16_nt<64, false><<<dim3(DMODEL / 64, M_TOTAL / 128), blk, 0, stream>>>(
        yb, wpf, b_proj, out, nullptr, nullptr, nullptr, M_TOTAL, DMODEL, DMODEL);
}

// Round 24
// 103.299 us; speedup vs baseline: 1.5049x; 1.0197x over previous
//
#include <hip/hip_runtime.h>
#include <hip/hip_bf16.h>

#define DMODEL 1024
#define NHEAD 16
#define HDIM 64
#define CTXLEN 2048
#define BATCH 2
#define M_TOTAL (BATCH * CTXLEN)   // 4096

typedef unsigned short ushort_t;
typedef __attribute__((ext_vector_type(8))) _Float16 f16x8;
typedef __attribute__((ext_vector_type(8))) unsigned short u16x8;
typedef __attribute__((ext_vector_type(4))) float f32x4;
typedef __attribute__((ext_vector_type(4))) unsigned short u16x4;

#define SCALE_LOG2 11.5415603271f   // 8 * log2(e) — folded into q at GEMM epilogue

// TRUE LPT dispatch order: units sorted by length descending (len-8 first,
// len-1 last). Previous u_off=79-(id>>5) left len-8 units (e.g. u_off 7)
// near the END of dispatch -> multi-us drain tail. Bijective over [0,80).
__constant__ int UORD[80] = {
    // len 8 (20)
    7, 20, 22, 23, 39, 42, 43, 45, 46, 47, 64, 68, 69, 72, 73, 74, 76, 77, 78, 79,
    // len 7 (30)
    6, 16, 18, 19, 21, 30, 33, 34, 36, 37, 38, 40, 41, 44, 48, 52, 53, 56, 57, 58,
    60, 61, 62, 63, 65, 66, 67, 70, 71, 75,
    // len 6 (19)
    5, 12, 14, 15, 17, 24, 25, 27, 28, 29, 31, 32, 35, 49, 50, 51, 54, 55, 59,
    // len 5 (6)
    4, 8, 10, 11, 13, 26,
    // len 4, 3, 2, 1
    3, 9, 2, 1, 0
};

__device__ __forceinline__ unsigned short f32_f16(float f) {
    return __builtin_bit_cast(unsigned short, (_Float16)f);
}
__device__ __forceinline__ float f16_f32(unsigned short h) {
    return (float)__builtin_bit_cast(_Float16, h);
}
__device__ __forceinline__ float fast_exp2(float x) {
    return __builtin_amdgcn_exp2f(x);
}
__device__ __forceinline__ f32x4 mfma16f(f16x8 a, f16x8 b, f32x4 c) {
    return __builtin_amdgcn_mfma_f32_16x16x32_f16(a, b, c, 0, 0, 0);
}
__device__ __forceinline__ void gload_lds16(const ushort_t* g, ushort_t* l) {
    __builtin_amdgcn_global_load_lds(
        (const __attribute__((address_space(1))) void*)g,
        (__attribute__((address_space(3))) void*)l, 16, 0, 0);
}
// units per q-tile: nu = qt/8+1; slot offset of first unit of qt within a bh
__device__ __forceinline__ int unit_off(int qt) {
    if (qt < 8)  return qt;
    if (qt < 16) return 8 + (qt - 8) * 2;
    if (qt < 24) return 24 + (qt - 16) * 3;
    return 48 + (qt - 24) * 4;
}

// ---------------------------------------------------------------------------
// fused f32 -> f16 convert for 3 arrays (one launch)
// ---------------------------------------------------------------------------
__global__ __launch_bounds__(256)
void conv3_f32_f16(const float* __restrict__ a, ushort_t* __restrict__ da, int na4,
                   const float* __restrict__ b, ushort_t* __restrict__ db, int nb4,
                   const float* __restrict__ c, ushort_t* __restrict__ dc, int nc4) {
    const int n = na4 + nb4 + nc4;
    for (int i = blockIdx.x * blockDim.x + threadIdx.x; i < n;
         i += gridDim.x * blockDim.x) {
        const float* s; ushort_t* d; int j = i;
        if (j < na4) { s = a; d = da; }
        else if (j - na4 < nb4) { j -= na4; s = b; d = db; }
        else { j -= na4 + nb4; s = c; d = dc; }
        const float4 v = reinterpret_cast<const float4*>(s)[j];
        u16x4 o;
        o[0] = f32_f16(v.x); o[1] = f32_f16(v.y);
        o[2] = f32_f16(v.z); o[3] = f32_f16(v.w);
        reinterpret_cast<u16x4*>(d)[j] = o;
    }
}

// ---------------------------------------------------------------------------
// fp16 MFMA GEMM (NT): C = A·B^T. BM=128, BN template (128 or 64), BK=64.
// XCD-aware bijective block swizzle. QKV_EPI: sec block-uniform;
//   sec 0/1: scatter q (prescaled) / k.  sec 2: V-transpose fused via LDS.
// ---------------------------------------------------------------------------
template<int BN, bool QKV_EPI>
__global__ __launch_bounds__(256)
void gemm_f16_nt(const ushort_t* __restrict__ A, const ushort_t* __restrict__ B,
                 const float* __restrict__ bias, float* __restrict__ C,
                 ushort_t* __restrict__ qf, ushort_t* __restrict__ kf,
                 ushort_t* __restrict__ vt,
                 int M, int N, int K) {
    constexpr int NF = BN / 32;
    constexpr int BOFF = 8192;
    constexpr int BCHUNK = BN * 8;
    constexpr int LDSZ = QKV_EPI ? 17408 : (BOFF + BN * 64);
    __shared__ ushort_t lds[LDSZ];

    int bx, by;
    {
        const int gx  = gridDim.x;
        const int nwg = gx * (int)gridDim.y;
        const int cpx = nwg >> 3;
        int flat = (int)blockIdx.y * gx + (int)blockIdx.x;
        flat = (flat & 7) * cpx + (flat >> 3);
        bx = flat % gx;
        by = flat / gx;
    }

    const int tid  = threadIdx.x;
    const int lane = tid & 63;
    const int wave = tid >> 6;
    const int lc   = lane & 15;
    const int lg   = lane >> 4;
    const int wr   = wave >> 1;
    const int wc   = wave & 1;
    const int row0 = by * 128;
    const int col0 = bx * BN;

    int aoff[4][2], boff[NF][2];
    #pragma unroll
    for (int m = 0; m < 4; ++m) {
        const int ra = wr * 64 + m * 16 + lc;
        #pragma unroll
        for (int kk = 0; kk < 2; ++kk)
            aoff[m][kk] = ra * 64 + (((kk * 4 + lg) ^ (ra & 7)) * 8);
    }
    #pragma unroll
    for (int n = 0; n < NF; ++n) {
        const int rb = wc * (NF * 16) + n * 16 + lc;
        #pragma unroll
        for (int kk = 0; kk < 2; ++kk)
            boff[n][kk] = rb * 64 + (((kk * 4 + lg) ^ (rb & 7)) * 8);
    }

    f32x4 acc[4][NF];
    const f32x4 zero4 = {0.f, 0.f, 0.f, 0.f};
    #pragma unroll
    for (int m = 0; m < 4; ++m)
        #pragma unroll
        for (int n = 0; n < NF; ++n) acc[m][n] = zero4;

    const int NT = K >> 6;

    auto stage = [&](int kt) {
        const int ko = kt * 64;
        #pragma unroll
        for (int i = 0; i < 4; ++i) {
            const int c  = tid + i * 256;
            const int r  = c >> 3;
            const int sg = (c & 7) ^ (r & 7);
            gload_lds16(A + (size_t)(row0 + r) * K + ko + sg * 8, &lds[c * 8]);
        }
        #pragma unroll
        for (int i = 0; i < BCHUNK / 256; ++i) {
            const int c  = tid + i * 256;
            const int r  = c >> 3;
            const int sg = (c & 7) ^ (r & 7);
            gload_lds16(B + (size_t)(col0 + r) * K + ko + sg * 8, &lds[BOFF + c * 8]);
        }
    };

    stage(0);
    for (int kt = 0; kt < NT; ++kt) {
        __syncthreads();
        f16x8 fa[2][4], fb[2][NF];
        #pragma unroll
        for (int kk = 0; kk < 2; ++kk) {
            #pragma unroll
            for (int m = 0; m < 4; ++m)
                fa[kk][m] = *reinterpret_cast<const f16x8*>(&lds[aoff[m][kk]]);
            #pragma unroll
            for (int n = 0; n < NF; ++n)
                fb[kk][n] = *reinterpret_cast<const f16x8*>(&lds[BOFF + boff[n][kk]]);
        }
        __syncthreads();
        if (kt + 1 < NT) stage(kt + 1);
        #pragma unroll
        for (int kk = 0; kk < 2; ++kk)
            #pragma unroll
            for (int m = 0; m < 4; ++m)
                #pragma unroll
                for (int n = 0; n < NF; ++n)
                    acc[m][n] = mfma16f(fa[kk][m], fb[kk][n], acc[m][n]);
    }

    if (!QKV_EPI) {
        #pragma unroll
        for (int m = 0; m < 4; ++m)
            #pragma unroll
            for (int i = 0; i < 4; ++i) {
                const int r = row0 + wr * 64 + m * 16 + lg * 4 + i;
                #pragma unroll
                for (int n = 0; n < NF; ++n) {
                    const int c = col0 + wc * (NF * 16) + n * 16 + lc;
                    C[(size_t)r * N + c] = acc[m][n][i] + bias[c];
                }
            }
    } else {
        const int sec_blk = col0 >> 10;   // block-uniform: 0=q, 1=k, 2=v
        if (sec_blk == 2) {
            __syncthreads();
            #pragma unroll
            for (int m = 0; m < 4; ++m)
                #pragma unroll
                for (int n = 0; n < NF; ++n) {
                    const int lcol = wc * (NF * 16) + n * 16 + lc;
                    const int lrow = wr * 64 + m * 16 + lg * 4;
                    u16x4 o;
                    #pragma unroll
                    for (int i = 0; i < 4; ++i) o[i] = f32_f16(acc[m][n][i]);
                    *reinterpret_cast<u16x4*>(&lds[lcol * 136 + lrow]) = o;
                }
            __syncthreads();
            const int bb   = row0 >> 11;
            const int t0   = row0 & 2047;
            const int lcol = tid >> 1;
            const int th   = (tid & 1) * 64;
            const int ch   = (col0 - 2048) + lcol;
            ushort_t* dst = vt + ((size_t)(bb * NHEAD + (ch >> 6)) * HDIM + (ch & 63)) * CTXLEN
                            + t0 + th;
            #pragma unroll
            for (int j = 0; j < 8; ++j)
                *reinterpret_cast<u16x8*>(&dst[j * 8]) =
                    *reinterpret_cast<const u16x8*>(&lds[lcol * 136 + th + j * 8]);
        } else {
            #pragma unroll
            for (int m = 0; m < 4; ++m)
                #pragma unroll
                for (int i = 0; i < 4; ++i) {
                    const int r = row0 + wr * 64 + m * 16 + lg * 4 + i;
                    const int bb = r >> 11;
                    const int t  = r & 2047;
                    #pragma unroll
                    for (int n = 0; n < NF; ++n) {
                        const int cg = col0 + wc * (NF * 16) + n * 16 + lc;
                        const int ch = cg & 1023;
                        const int hh = ch >> 6;
                        const int d  = ch & 63;
                        const size_t off = (((size_t)(bb * NHEAD + hh)) * CTXLEN + t) * HDIM + d;
                        float v = acc[m][n][i];
                        if (sec_blk == 0) {
                            qf[off] = f32_f16(v * SCALE_LOG2);
                        } else {
                            kf[off] = f32_f16(v);
                        }
                    }
                }
        }
    }
}

// ---------------------------------------------------------------------------
// Flash causal attention: split-KV v7 (QBLK=64, units <=8 steps, grid 2560)
// + TRUE length-sorted LPT dispatch (UORD) + defer-max + prescaled q.
// nu==1 units (qt<8) write yb directly.
// ---------------------------------------------------------------------------
__global__ __launch_bounds__(256)
void attn_fwd7(const ushort_t* __restrict__ qf, const ushort_t* __restrict__ kf,
               const ushort_t* __restrict__ vt,
               ushort_t* __restrict__ py, float* __restrict__ pml,
               ushort_t* __restrict__ yb) {
    __shared__ ushort_t KH[2][4096];
    __shared__ ushort_t VT[2][4096];
    __shared__ ushort_t Ps[4][16][64];

    const int id    = blockIdx.x;
    const int bh    = id & 31;
    const int u_off = UORD[id >> 5];           // length-sorted LPT order
    int qt, u;
    if (u_off < 8)       { qt = u_off;                          u = 0; }
    else if (u_off < 24) { const int t = u_off - 8;  qt = 8  + (t >> 1); u = t & 1; }
    else if (u_off < 48) { const int t = u_off - 24; const int q3 = t / 3; qt = 16 + q3; u = t - q3 * 3; }
    else                 { const int t = u_off - 48; qt = 24 + (t >> 2); u = t & 3; }
    const int total = qt + 1;
    const int nu    = (qt >> 3) + 1;
    const int base  = total / nu, rem = total % nu;
    const int kb0   = u * base + (u < rem ? u : rem);
    const int len   = base + (u < rem ? 1 : 0);
    const int slot  = bh * 80 + u_off;

    const int tid  = threadIdx.x;
    const int wave = tid >> 6;
    const int lane = tid & 63;
    const int lc   = lane & 15;
    const int lg   = lane >> 4;

    const ushort_t* kfb = kf + (size_t)bh * CTXLEN * HDIM;
    const ushort_t* vtb = vt + (size_t)bh * HDIM * CTXLEN;

    const int cA = tid, cB = 256 + tid;
    const int rA = cA >> 3, sgA = (cA & 7) ^ (rA & 7);
    const int rB = cB >> 3, sgB = (cB & 7) ^ (rB & 7);

    auto stage = [&](int kb, int buf) {
        const size_t koff = (size_t)(kb * 64);
        gload_lds16(kfb + (koff + rA) * HDIM + sgA * 8, &KH[buf][cA * 8]);
        gload_lds16(kfb + (koff + rB) * HDIM + sgB * 8, &KH[buf][cB * 8]);
        gload_lds16(vtb + (size_t)rA * CTXLEN + kb * 64 + sgA * 8, &VT[buf][cA * 8]);
        gload_lds16(vtb + (size_t)rB * CTXLEN + kb * 64 + sgB * 8, &VT[buf][cB * 8]);
    };

    // Q fragments: q row = qt*64 + wave*16 + lc  (q prescaled by 8*log2e)
    const size_t qrow = (size_t)bh * CTXLEN + qt * 64 + wave * 16 + lc;
    f16x8 qfr[2];
    #pragma unroll
    for (int ds = 0; ds < 2; ++ds)
        qfr[ds] = *reinterpret_cast<const f16x8*>(&qf[qrow * HDIM + ds * 32 + lg * 8]);

    const f32x4 zero4 = {0.f, 0.f, 0.f, 0.f};
    f32x4 yacc[4];   // y^T: d = t*16+lg*4+i, q = lc
    #pragma unroll
    for (int t = 0; t < 4; ++t) yacc[t] = zero4;
    float m_i = -1e30f, l_i = 0.f;

    stage(kb0, 0);
    __syncthreads();

    int cur = 0;
    for (int s = 0; s < len; ++s) {
        const int kb = kb0 + s;
        if (s + 1 < len) stage(kb + 1, cur ^ 1);

        f16x8 kfr[4][2];
        #pragma unroll
        for (int tc = 0; tc < 4; ++tc) {
            const int rk = tc * 16 + lc;
            #pragma unroll
            for (int ds = 0; ds < 2; ++ds) {
                const int a = rk * 64 + (((ds * 4 + lg) ^ (rk & 7)) * 8);
                kfr[tc][ds] = *reinterpret_cast<const f16x8*>(&KH[cur][a]);
            }
        }
        f16x8 vf[4][2];
        #pragma unroll
        for (int t = 0; t < 4; ++t) {
            const int rv = t * 16 + lc;
            #pragma unroll
            for (int ks = 0; ks < 2; ++ks) {
                const int a = rv * 64 + (((ks * 4 + lg) ^ (rv & 7)) * 8);
                vf[t][ks] = *reinterpret_cast<const f16x8*>(&VT[cur][a]);
            }
        }

        f32x4 sacc[4];
        #pragma unroll
        for (int tc = 0; tc < 4; ++tc) sacc[tc] = zero4;
        __builtin_amdgcn_s_setprio(1);
        #pragma unroll
        for (int tc = 0; tc < 4; ++tc)
            #pragma unroll
            for (int ds = 0; ds < 2; ++ds)
                sacc[tc] = mfma16f(kfr[tc][ds], qfr[ds], sacc[tc]);
        __builtin_amdgcn_s_setprio(0);

        float p[4][4];
        #pragma unroll
        for (int tc = 0; tc < 4; ++tc)
            #pragma unroll
            for (int i = 0; i < 4; ++i)
                p[tc][i] = sacc[tc][i];
        if (kb == qt) {   // diagonal tile only: causal mask (wave-uniform branch)
            const int q_loc = wave * 16 + lc;
            #pragma unroll
            for (int tc = 0; tc < 4; ++tc)
                #pragma unroll
                for (int i = 0; i < 4; ++i)
                    if ((tc * 16 + lg * 4 + i) > q_loc) p[tc][i] = -1e30f;
        }
        float mx = p[0][0];
        #pragma unroll
        for (int tc = 0; tc < 4; ++tc)
            #pragma unroll
            for (int i = 0; i < 4; ++i) mx = fmaxf(mx, p[tc][i]);
        mx = fmaxf(mx, __shfl_xor(mx, 16));
        mx = fmaxf(mx, __shfl_xor(mx, 32));

        if (__all(mx <= m_i + 8.0f)) {
            // defer-max: keep m_i, skip corr/rescale (p <= 2^8, f16-safe)
            float psum = 0.f;
            #pragma unroll
            for (int tc = 0; tc < 4; ++tc)
                #pragma unroll
                for (int i = 0; i < 4; ++i) {
                    const float e = fast_exp2(p[tc][i] - m_i);
                    p[tc][i] = e;
                    psum += e;
                }
            psum += __shfl_xor(psum, 16);
            psum += __shfl_xor(psum, 32);
            l_i += psum;
        } else {
            const float mnew = fmaxf(m_i, mx);
            const float corr = fast_exp2(m_i - mnew);
            float psum = 0.f;
            #pragma unroll
            for (int tc = 0; tc < 4; ++tc)
                #pragma unroll
                for (int i = 0; i < 4; ++i) {
                    const float e = fast_exp2(p[tc][i] - mnew);
                    p[tc][i] = e;
                    psum += e;
                }
            psum += __shfl_xor(psum, 16);
            psum += __shfl_xor(psum, 32);
            l_i = l_i * corr + psum;
            m_i = mnew;
            #pragma unroll
            for (int t = 0; t < 4; ++t) yacc[t] *= corr;
        }

        // P -> Ps (wave-private, swizzled, u16x4 chunks)
        #pragma unroll
        for (int tc = 0; tc < 4; ++tc) {
            const int eb = tc * 16 + lg * 4;
            const int se = ((((eb >> 3) ^ (lc & 7)) << 3) | (eb & 7));
            u16x4 pk;
            #pragma unroll
            for (int i = 0; i < 4; ++i) pk[i] = f32_f16(p[tc][i]);
            *reinterpret_cast<u16x4*>(&Ps[wave][lc][se]) = pk;
        }
        f16x8 pa[2];
        #pragma unroll
        for (int ks = 0; ks < 2; ++ks) {
            const int sl = ((ks * 4 + lg) ^ (lc & 7)) << 3;
            pa[ks] = *reinterpret_cast<const f16x8*>(&Ps[wave][lc][sl]);
        }
        // y^T += V^T P
        __builtin_amdgcn_s_setprio(1);
        #pragma unroll
        for (int t = 0; t < 4; ++t)
            #pragma unroll
            for (int ks = 0; ks < 2; ++ks)
                yacc[t] = mfma16f(vf[t][ks], pa[ks], yacc[t]);
        __builtin_amdgcn_s_setprio(0);

        __syncthreads();
        cur ^= 1;
    }

    const int row = wave * 16 + lc;
    if (nu == 1) {
        // single-unit q-tile (qt < 8): normalize and write final y directly
        const float inv = 1.0f / l_i;
        const int b = bh >> 4, h = bh & 15;
        ushort_t* dst = yb + (size_t)(b * CTXLEN + qt * 64 + row) * DMODEL + h * HDIM;
        #pragma unroll
        for (int t = 0; t < 4; ++t) {
            u16x4 o;
            #pragma unroll
            for (int i = 0; i < 4; ++i) o[i] = f32_f16(yacc[t][i] * inv);
            *reinterpret_cast<u16x4*>(&dst[t * 16 + lg * 4]) = o;
        }
    } else {
        // partial epilogue: unnormalized y (f16) + m,l (f32)
        ushort_t* prow = py + ((size_t)slot * 64 + row) * 64;
        #pragma unroll
        for (int t = 0; t < 4; ++t) {
            u16x4 o;
            #pragma unroll
            for (int i = 0; i < 4; ++i) o[i] = f32_f16(yacc[t][i]);
            *reinterpret_cast<u16x4*>(&prow[t * 16 + lg * 4]) = o;
        }
        if (lg == 0) {
            pml[(size_t)slot * 128 + row]      = m_i;
            pml[(size_t)slot * 128 + 64 + row] = l_i;
        }
    }
}

// ---------------------------------------------------------------------------
// Merge split-KV partials for qt >= 8 only. Grid (24, 32): x = qt-8, y = bh.
// ---------------------------------------------------------------------------
__global__ __launch_bounds__(256)
void merge_attn(const ushort_t* __restrict__ py, const float* __restrict__ pml,
                ushort_t* __restrict__ yb) {
    const int qt  = 8 + blockIdx.x;
    const int bh  = blockIdx.y;
    const int b   = bh >> 4;
    const int h   = bh & 15;
    const int tid = threadIdx.x;
    const int row = tid >> 2;
    const int d0  = (tid & 3) * 16;

    const int nu    = (qt >> 3) + 1;
    const int sbase = bh * 80 + unit_off(qt);

    float mu[4], lu[4];
    float M = -1e30f;
    #pragma unroll
    for (int u = 0; u < 4; ++u) {
        if (u < nu) {
            mu[u] = pml[(size_t)(sbase + u) * 128 + row];
            lu[u] = pml[(size_t)(sbase + u) * 128 + 64 + row];
            M = fmaxf(M, mu[u]);
        } else { mu[u] = -1e30f; lu[u] = 0.f; }
    }
    float w[4], ltot = 0.f;
    #pragma unroll
    for (int u = 0; u < 4; ++u) {
        w[u] = (u < nu) ? fast_exp2(mu[u] - M) : 0.f;
        ltot += w[u] * lu[u];
    }

    float y[16];
    #pragma unroll
    for (int j = 0; j < 16; ++j) y[j] = 0.f;
    #pragma unroll
    for (int u = 0; u < 4; ++u) {
        if (u < nu) {
            const ushort_t* pr = py + ((size_t)(sbase + u) * 64 + row) * 64 + d0;
            const u16x8 a = *reinterpret_cast<const u16x8*>(&pr[0]);
            const u16x8 c = *reinterpret_cast<const u16x8*>(&pr[8]);
            #pragma unroll
            for (int j = 0; j < 8; ++j) {
                y[j]     += w[u] * f16_f32(a[j]);
                y[8 + j] += w[u] * f16_f32(c[j]);
            }
        }
    }
    const float inv = 1.0f / ltot;
    ushort_t* dst = yb + (size_t)(b * CTXLEN + qt * 64 + row) * DMODEL + h * HDIM + d0;
    u16x8 o0, o1;
    #pragma unroll
    for (int j = 0; j < 8; ++j) {
        o0[j] = f32_f16(y[j] * inv);
        o1[j] = f32_f16(y[8 + j] * inv);
    }
    *reinterpret_cast<u16x8*>(&dst[0]) = o0;
    *reinterpret_cast<u16x8*>(&dst[8]) = o1;
}

// ---------------------------------------------------------------------------
extern "C" void kernel_launch(void* const* d_in, const int* in_sizes, int n_in,
                              void* d_out, int out_size, void* d_ws, size_t ws_size,
                              hipStream_t stream) {
    const float* x      = (const float*)d_in[0];
    const float* w_qkv  = (const float*)d_in[1];
    const float* w_proj = (const float*)d_in[2];
    const float* b_proj = (const float*)d_in[3];
    float* out = (float*)d_out;

    // ws layout (bytes):
    //   wqf f16 [3072,1024]                 @ 0          (6,291,456)
    //   wpf f16 [1024,1024]                 @ 6291456    (2,097,152)
    //   xf  f16 [4096,1024] | yb f16 reuse  @ 8388608    (8,388,608)
    //   qf  f16 [32][2048][64]              @ 16777216   (8,388,608)
    //   kf  f16 [32][2048][64]              @ 25165824   (8,388,608)
    //   (gap)                               @ 33554432   (8,388,608)
    //   vt  f16 [32][64][2048]              @ 41943040   (8,388,608)
    //   py  f16 [2560][64][64]              @ 50331648   (20,971,520)
    //   pml f32 [2560][128]                 @ 71303168   ( 1,310,720)
    char* ws = (char*)d_ws;
    ushort_t* wqf = (ushort_t*)(ws);
    ushort_t* wpf = (ushort_t*)(ws + 6291456);
    ushort_t* xf  = (ushort_t*)(ws + 8388608);
    ushort_t* qf  = (ushort_t*)(ws + 16777216);
    ushort_t* kf  = (ushort_t*)(ws + 25165824);
    ushort_t* vt  = (ushort_t*)(ws + 41943040);
    ushort_t* py  = (ushort_t*)(ws + 50331648);
    float*    pml = (float*)   (ws + 71303168);
    ushort_t* yb  = xf;   // reused after qkv GEMM consumed xf

    const dim3 blk(256);

    // one fused convert launch: x, w_qkv, w_proj -> f16
    conv3_f32_f16<<<dim3(2048), blk, 0, stream>>>(
        x, xf, M_TOTAL * DMODEL / 4,
        w_qkv, wqf, 3 * DMODEL * DMODEL / 4,
        w_proj, wpf, DMODEL * DMODEL / 4);

    // qkv = x @ w_qkv^T (N=3072, BK=64); epilogue scatters q (prescaled) / k
    // and writes v TRANSPOSED (vt) directly — no separate transpose kernel
    gemm_f16_nt<128, true><<<dim3(3 * DMODEL / 128, M_TOTAL / 128), blk, 0, stream>>>(
        xf, wqf, nullptr, nullptr, qf, kf, vt, M_TOTAL, 3 * DMODEL, DMODEL);

    // split-KV attention units (length-sorted LPT; qt<8 write yb directly) + merge
    attn_fwd7<<<dim3(2560), blk, 0, stream>>>(qf, kf, vt, py, pml, yb);
    merge_attn<<<dim3(24, 32), blk, 0, stream>>>(py, pml, yb);

    // out = y @ w_proj^T + b  — BN=64 tiles, BK=64 -> 512 blocks (2/CU)
    gemm_f16_nt<64, false><<<dim3(DMODEL / 64, M_TOTAL / 128), blk, 0, stream>>>(
        yb, wpf, b_proj, out, nullptr, nullptr, nullptr, M_TOTAL, DMODEL, DMODEL);
}